// Round 3
// baseline (18.242 us; speedup 1.0000x reference)
//
#include <hip/hip_runtime.h>

#define NS 32
#define NH 32
#define C2L 2.8853900817779268f  // 2*log2(e): e^(2x) = 2^(C2L*x)

// 4 threads per point; thread j handles segment s0+j (the only <=4 segments
// with nonzero cosine window). Weights in LDS transposed [h][s] so per-lane
// segment gathers are bank-conflict-free. (W1,b1) pre-scaled by 2*log2(e)
// so the exp2 argument is a single fma.
__global__ __launch_bounds__(256) void springnn_kernel(
    const float* __restrict__ t_in,
    const float* __restrict__ W1,   // [S][1][H]
    const float* __restrict__ b1,   // [S][H]
    const float* __restrict__ W2,   // [S][H][1]
    const float* __restrict__ b2,   // [S][1]
    float* __restrict__ out,
    int N)
{
    __shared__ float2 w1b1[NH][NS];  // [h][s] = (W1*C2L, b1*C2L)
    __shared__ float  w2m2[NH][NS];  // [h][s] = -2 * W2
    __shared__ float  b2eff[NS];     // b2[s] + sum_h W2[s][h]  (tanh folding)

    const int tid = threadIdx.x;

    // ---- stage weights into LDS (transposed) ----
    for (int idx = tid; idx < NS * NH; idx += 256) {
        const int s = idx >> 5;
        const int h = idx & 31;
        w1b1[h][s] = make_float2(W1[s * NH + h] * C2L, b1[s * NH + h] * C2L);
        w2m2[h][s] = -2.0f * W2[s * NH + h];
    }
    if (tid < NS) {
        float acc = b2[tid];
        const float4* w2v = (const float4*)(W2 + tid * NH);
        #pragma unroll
        for (int q = 0; q < NH / 4; ++q) {
            float4 v = w2v[q];
            acc += (v.x + v.y) + (v.z + v.w);
        }
        b2eff[tid] = acc;
    }
    __syncthreads();

    const int gid = blockIdx.x * 256 + tid;
    const int n = gid >> 2;          // point index
    const int j = tid & 3;           // segment slot 0..3
    if (n >= N) return;
    const float t = t_in[n];

    // d_j = t - (ceil(t-2)+j) lies in (-2,2] for j=0..3 -> always in support.
    const int s = (int)ceilf(t - 2.0f) + j;

    float val = 0.0f;
    if (s >= 0 && s < NS) {
        const float d = t - (float)s;
        // window = (1+cos(pi*d/2))/2 = cos^2(pi*d/4); v_cos takes revolutions
        const float c = __builtin_amdgcn_cosf(d * 0.125f);

        float o0 = b2eff[s], o1 = 0.0f;   // two chains for ILP
        #pragma unroll 8
        for (int h = 0; h < NH; h += 2) {
            const float2 wb0 = w1b1[h][s];
            const float2 wb1 = w1b1[h + 1][s];
            const float e0 = __builtin_amdgcn_exp2f(fmaf(t, wb0.x, wb0.y));
            const float e1 = __builtin_amdgcn_exp2f(fmaf(t, wb1.x, wb1.y));
            o0 = fmaf(w2m2[h][s],     __builtin_amdgcn_rcpf(e0 + 1.0f), o0);
            o1 = fmaf(w2m2[h + 1][s], __builtin_amdgcn_rcpf(e1 + 1.0f), o1);
        }
        val = c * c * (o0 + o1);
    }

    // sum the 4 segment partials (lanes j=0..3 within an aligned 4-lane group)
    val += __shfl_xor(val, 1, 64);
    val += __shfl_xor(val, 2, 64);
    if (j == 0) out[n] = val;
}

extern "C" void kernel_launch(void* const* d_in, const int* in_sizes, int n_in,
                              void* d_out, int out_size, void* d_ws, size_t ws_size,
                              hipStream_t stream) {
    const float* t  = (const float*)d_in[0];
    const float* W1 = (const float*)d_in[1];
    const float* b1 = (const float*)d_in[2];
    const float* W2 = (const float*)d_in[3];
    const float* b2 = (const float*)d_in[4];
    float* outp = (float*)d_out;
    const int N = in_sizes[0];

    const int block = 256;
    const long long threads = (long long)N * 4;
    const int grid = (int)((threads + block - 1) / block);
    springnn_kernel<<<grid, block, 0, stream>>>(t, W1, b1, W2, b2, outp, N);
}